// Round 2
// baseline (494.332 us; speedup 1.0000x reference)
//
#include <hip/hip_runtime.h>

typedef unsigned short u16;
typedef unsigned int u32;
typedef __attribute__((ext_vector_type(8))) short short8;
typedef __attribute__((ext_vector_type(4))) float f32x4;

#define BB 8
#define CCH 256
#define HH 64
#define WW 64
#define HP 66
#define NPOS 4096
#define KTOT 2304

// ---- ws layout (bytes) ----
#define XT_BYTES   35684352ull                 // fp32 [8][66][66][256]
#define W2R_OFF    35684352ull                 // bf16 [256][2304]
#define WOFF2_OFF  36864000ull                 // bf16 [32][2304]
#define OFFWS_OFF  37011456ull                 // fp32 [8][4096][18]
#define GOFF_OFF   39370752ull                 // int4 [8*9*4096]
#define GW_OFF     44089344ull                 // float4 [8*9*4096]
#define WS_NEED    48807936ull

__device__ __forceinline__ float bf2f(u16 u) {
    union { u32 u; float f; } v; v.u = ((u32)u) << 16; return v.f;
}
__device__ __forceinline__ u16 f2bf(float f) {
    union { float f; u32 u; } v; v.f = f;
    u32 r = v.u + 0x7FFFu + ((v.u >> 16) & 1u);
    return (u16)(r >> 16);
}
__device__ __forceinline__ u32 pk2(float a, float b) {
    return (u32)f2bf(a) | ((u32)f2bf(b) << 16);
}

// ---- K0: reorder weights (fp32 -> bf16): W2r[o][k*256+c] = w[o][c][k]; Woff2 32 rows (>=18 zero) ----
__global__ void k_prep(const float* __restrict__ w, const float* __restrict__ w_off,
                       u16* __restrict__ W2r, u16* __restrict__ Woff2) {
    int t = blockIdx.x * 256 + threadIdx.x;
    if (t < CCH * KTOT) {
        int o = t / KTOT, kk = t % KTOT, k = kk >> 8, c = kk & 255;
        W2r[t] = f2bf(w[(o * CCH + c) * 9 + k]);
    } else {
        int u = t - CCH * KTOT;   // u < 32*2304 exactly by grid sizing
        int o = u / KTOT, kk = u % KTOT, k = kk >> 8, c = kk & 255;
        Woff2[u] = (o < 18) ? f2bf(w_off[(o * CCH + c) * 9 + k]) : (u16)0;
    }
}

// ---- K1: transpose+pad: xT[b][y+1][x+1][c] = x[b][c][y][x]; borders pre-zeroed by memset ----
__global__ __launch_bounds__(256) void k_transpose(const float* __restrict__ x, float* __restrict__ xT) {
    __shared__ __align__(16) float T[64][72];
    int b = blockIdx.z, y = blockIdx.y, c0 = blockIdx.x * 64;
    int t = threadIdx.x;
    {
        int i = t >> 2, seg = t & 3;   // channel i, 16-float x-segment
        const float* src = x + (((size_t)(b * CCH + c0 + i) * HH + y) * WW) + seg * 16;
        float4 v0 = *(const float4*)(src);
        float4 v1 = *(const float4*)(src + 4);
        float4 v2 = *(const float4*)(src + 8);
        float4 v3 = *(const float4*)(src + 12);
        *(float4*)&T[i][seg * 16]      = v0;
        *(float4*)&T[i][seg * 16 + 4]  = v1;
        *(float4*)&T[i][seg * 16 + 8]  = v2;
        *(float4*)&T[i][seg * 16 + 12] = v3;
    }
    __syncthreads();
    {
        int xc = t >> 2, cs = t & 3;   // x-position xc, 16-channel segment cs
        float* dst = xT + (((size_t)(b * HP + y + 1) * HP) + (xc + 1)) * CCH + c0 + cs * 16;
#pragma unroll
        for (int h = 0; h < 4; ++h) {
            float4 o4;
            o4.x = T[cs * 16 + h * 4 + 0][xc];
            o4.y = T[cs * 16 + h * 4 + 1][xc];
            o4.z = T[cs * 16 + h * 4 + 2][xc];
            o4.w = T[cs * 16 + h * 4 + 3][xc];
            *(float4*)(dst + h * 4) = o4;
        }
    }
}

// ---- K2: offset conv as MFMA GEMM, M=32(18 used), N=128/block, K=2304 ----
__global__ __launch_bounds__(256) void k_offconv(const float* __restrict__ xT,
                                                 const u16* __restrict__ Woff2,
                                                 const float* __restrict__ b_off,
                                                 float* __restrict__ off_ws) {
    __shared__ __align__(16) u16 As[32 * 40];
    __shared__ __align__(16) u16 Bs[128 * 40];
    int b = blockIdx.y;
    int pos0 = blockIdx.x * 128;
    int t = threadIdx.x, lane = t & 63, wv = t >> 6;
    int pos_l = t & 127, jp = t >> 7;
    int posg = pos0 + pos_l, py_ = posg >> 6, px_ = posg & 63;

    f32x4 acc[2][2];
    f32x4 z = {0.f, 0.f, 0.f, 0.f};
    acc[0][0] = z; acc[0][1] = z; acc[1][0] = z; acc[1][1] = z;

    for (int kk = 0; kk < KTOT; kk += 32) {
        int k9 = kk >> 8, c0 = kk & 255;
        int ky = k9 / 3, kx = k9 % 3;
        __syncthreads();
        if (t < 128) {
            int row = t >> 2, h = t & 3;
            uint4 v = *(const uint4*)(Woff2 + row * KTOT + kk + h * 8);
            *(uint4*)&As[row * 40 + h * 8] = v;
        }
        {
            const float* src = xT + ((size_t)((b * HP + py_ + ky) * HP) + px_ + kx) * CCH + c0 + jp * 16;
            float4 s0 = *(const float4*)(src);
            float4 s1 = *(const float4*)(src + 4);
            float4 s2 = *(const float4*)(src + 8);
            float4 s3 = *(const float4*)(src + 12);
            uint4 d0, d1;
            d0.x = pk2(s0.x, s0.y); d0.y = pk2(s0.z, s0.w); d0.z = pk2(s1.x, s1.y); d0.w = pk2(s1.z, s1.w);
            d1.x = pk2(s2.x, s2.y); d1.y = pk2(s2.z, s2.w); d1.z = pk2(s3.x, s3.y); d1.w = pk2(s3.z, s3.w);
            *(uint4*)&Bs[pos_l * 40 + jp * 16] = d0;
            *(uint4*)&Bs[pos_l * 40 + jp * 16 + 8] = d1;
        }
        __syncthreads();
        int q = lane >> 4, m = lane & 15;
        short8 a0 = *(const short8*)&As[m * 40 + q * 8];
        short8 a1 = *(const short8*)&As[(16 + m) * 40 + q * 8];
        short8 b0 = *(const short8*)&Bs[(wv * 32 + m) * 40 + q * 8];
        short8 b1 = *(const short8*)&Bs[(wv * 32 + 16 + m) * 40 + q * 8];
        acc[0][0] = __builtin_amdgcn_mfma_f32_16x16x32_bf16(a0, b0, acc[0][0], 0, 0, 0);
        acc[0][1] = __builtin_amdgcn_mfma_f32_16x16x32_bf16(a0, b1, acc[0][1], 0, 0, 0);
        acc[1][0] = __builtin_amdgcn_mfma_f32_16x16x32_bf16(a1, b0, acc[1][0], 0, 0, 0);
        acc[1][1] = __builtin_amdgcn_mfma_f32_16x16x32_bf16(a1, b1, acc[1][1], 0, 0, 0);
    }
    int q = lane >> 4, nn = lane & 15;
#pragma unroll
    for (int ao = 0; ao < 2; ++ao)
#pragma unroll
        for (int bn = 0; bn < 2; ++bn) {
            int pos = pos0 + wv * 32 + bn * 16 + nn;
#pragma unroll
            for (int r = 0; r < 4; ++r) {
                int o = ao * 16 + q * 4 + r;
                if (o < 18) {
                    off_ws[((size_t)(b << 12) + pos) * 18 + o] = acc[ao][bn][r] + b_off[o];
                }
            }
        }
}

// ---- K3: per-(b,k,pos) corner offsets + bilinear weights ----
__global__ void k_coords(const float* __restrict__ off_ws, int4* __restrict__ G_off,
                         float4* __restrict__ G_w) {
    int t = blockIdx.x * 256 + threadIdx.x;   // 294912 total
    int b = t / 36864;
    int r = t - b * 36864;
    int k = r >> 12;
    int pos = r & 4095;
    int y = pos >> 6, x = pos & 63;
    const float* ow = off_ws + ((size_t)(b << 12) + pos) * 18;
    float dy = ow[2 * k], dx = ow[2 * k + 1];
    float pyf = (float)(y - 1 + k / 3) + dy;
    float pxf = (float)(x - 1 + k % 3) + dx;
    float y0f = floorf(pyf), x0f = floorf(pxf);
    int y0 = (int)y0f, x0 = (int)x0f;
    int y1 = y0 + 1, x1 = x0 + 1;
    float wy1 = pyf - y0f, wy0 = 1.f - wy1;
    float wx1 = pxf - x0f, wx0 = 1.f - wx1;
    bool vy0 = (y0 >= 0) & (y0 < HH), vy1 = (y1 >= 0) & (y1 < HH);
    bool vx0 = (x0 >= 0) & (x0 < WW), vx1 = (x1 >= 0) & (x1 < WW);
    int yc0 = min(max(y0, 0), HH - 1), yc1 = min(max(y1, 0), HH - 1);
    int xc0 = min(max(x0, 0), WW - 1), xc1 = min(max(x1, 0), WW - 1);
    int base = b * HP * HP * CCH;
    int4 go;
    go.x = base + ((yc0 + 1) * HP + (xc0 + 1)) * CCH;
    go.y = base + ((yc0 + 1) * HP + (xc1 + 1)) * CCH;
    go.z = base + ((yc1 + 1) * HP + (xc0 + 1)) * CCH;
    go.w = base + ((yc1 + 1) * HP + (xc1 + 1)) * CCH;
    float4 gw;
    gw.x = (vy0 & vx0) ? wy0 * wx0 : 0.f;
    gw.y = (vy0 & vx1) ? wy0 * wx1 : 0.f;
    gw.z = (vy1 & vx0) ? wy1 * wx0 : 0.f;
    gw.w = (vy1 & vx1) ? wy1 * wx1 : 0.f;
    G_off[t] = go;
    G_w[t] = gw;
}

// ---- K4: main deformable GEMM: 128x128 tile, fused bilinear B-staging, sigmoid epilogue ----
__global__ __launch_bounds__(256) void k_main(const float* __restrict__ xT,
                                              const u16* __restrict__ W2r,
                                              const int4* __restrict__ G_off,
                                              const float4* __restrict__ G_w,
                                              const float* __restrict__ bias,
                                              float* __restrict__ out) {
    __shared__ __align__(16) u16 As[128 * 40];
    __shared__ __align__(16) u16 Bs[128 * 40];
    int b = blockIdx.z;
    int o0 = blockIdx.y * 128;
    int pos0 = blockIdx.x * 128;
    int t = threadIdx.x, lane = t & 63, wv = t >> 6;
    int wr = wv >> 1, wc = wv & 1;
    int pos_l = t & 127, jp = t >> 7;
    int arow = t >> 1, ah = t & 1;

    f32x4 acc[4][4];
    f32x4 z = {0.f, 0.f, 0.f, 0.f};
#pragma unroll
    for (int i = 0; i < 4; ++i)
#pragma unroll
        for (int j = 0; j < 4; ++j) acc[i][j] = z;

    for (int kk = 0; kk < KTOT; kk += 32) {
        int k9 = kk >> 8, c0 = kk & 255;
        __syncthreads();
        // A: 128 x 32 bf16
        {
            const u16* s = W2r + (size_t)(o0 + arow) * KTOT + kk + ah * 16;
            uint4 v0 = *(const uint4*)s;
            uint4 v1 = *(const uint4*)(s + 8);
            *(uint4*)&As[arow * 40 + ah * 16] = v0;
            *(uint4*)&As[arow * 40 + ah * 16 + 8] = v1;
        }
        // B: 32 x 128 via 4-corner bilinear gather (fp32 -> bf16 pack)
        {
            int g = ((b * 9 + k9) << 12) + pos0 + pos_l;
            int4 go = G_off[g];
            float4 gw = G_w[g];
#pragma unroll
            for (int oc = 0; oc < 2; ++oc) {
                int c8 = c0 + jp * 16 + oc * 8;
                const float* p0 = xT + go.x + c8;
                const float* p1 = xT + go.y + c8;
                const float* p2 = xT + go.z + c8;
                const float* p3 = xT + go.w + c8;
                float4 a0 = *(const float4*)p0, a0b = *(const float4*)(p0 + 4);
                float4 a1 = *(const float4*)p1, a1b = *(const float4*)(p1 + 4);
                float4 a2 = *(const float4*)p2, a2b = *(const float4*)(p2 + 4);
                float4 a3 = *(const float4*)p3, a3b = *(const float4*)(p3 + 4);
                float v0 = gw.x * a0.x + gw.y * a1.x + gw.z * a2.x + gw.w * a3.x;
                float v1 = gw.x * a0.y + gw.y * a1.y + gw.z * a2.y + gw.w * a3.y;
                float v2 = gw.x * a0.z + gw.y * a1.z + gw.z * a2.z + gw.w * a3.z;
                float v3 = gw.x * a0.w + gw.y * a1.w + gw.z * a2.w + gw.w * a3.w;
                float v4 = gw.x * a0b.x + gw.y * a1b.x + gw.z * a2b.x + gw.w * a3b.x;
                float v5 = gw.x * a0b.y + gw.y * a1b.y + gw.z * a2b.y + gw.w * a3b.y;
                float v6 = gw.x * a0b.z + gw.y * a1b.z + gw.z * a2b.z + gw.w * a3b.z;
                float v7 = gw.x * a0b.w + gw.y * a1b.w + gw.z * a2b.w + gw.w * a3b.w;
                uint4 pkd;
                pkd.x = pk2(v0, v1); pkd.y = pk2(v2, v3);
                pkd.z = pk2(v4, v5); pkd.w = pk2(v6, v7);
                *(uint4*)&Bs[pos_l * 40 + jp * 16 + oc * 8] = pkd;
            }
        }
        __syncthreads();
        int q = lane >> 4, m = lane & 15;
        short8 af[4], bfr[4];
#pragma unroll
        for (int ao = 0; ao < 4; ++ao)
            af[ao] = *(const short8*)&As[(wr * 64 + ao * 16 + m) * 40 + q * 8];
#pragma unroll
        for (int bn = 0; bn < 4; ++bn)
            bfr[bn] = *(const short8*)&Bs[(wc * 64 + bn * 16 + m) * 40 + q * 8];
#pragma unroll
        for (int ao = 0; ao < 4; ++ao)
#pragma unroll
            for (int bn = 0; bn < 4; ++bn)
                acc[ao][bn] = __builtin_amdgcn_mfma_f32_16x16x32_bf16(af[ao], bfr[bn], acc[ao][bn], 0, 0, 0);
    }
    // epilogue: bias + sigmoid -> fp32 NCHW
    int q = lane >> 4, nn = lane & 15;
#pragma unroll
    for (int ao = 0; ao < 4; ++ao) {
        int ob = o0 + wr * 64 + ao * 16 + q * 4;
#pragma unroll
        for (int bn = 0; bn < 4; ++bn) {
            int pos = pos0 + wc * 64 + bn * 16 + nn;
#pragma unroll
            for (int r = 0; r < 4; ++r) {
                float v = acc[ao][bn][r] + bias[ob + r];
                float sg = 1.0f / (1.0f + __expf(-v));
                out[(size_t)((b * CCH + ob + r) * NPOS) + pos] = sg;
            }
        }
    }
}

extern "C" void kernel_launch(void* const* d_in, const int* in_sizes, int n_in,
                              void* d_out, int out_size, void* d_ws, size_t ws_size,
                              hipStream_t stream) {
    if (ws_size < WS_NEED) return;  // insufficient scratch — fail visibly rather than corrupt
    const float* x     = (const float*)d_in[0];
    const float* w_off = (const float*)d_in[1];
    const float* b_off = (const float*)d_in[2];
    const float* w     = (const float*)d_in[3];
    const float* bias  = (const float*)d_in[4];
    float* out = (float*)d_out;

    char* ws = (char*)d_ws;
    float* xT      = (float*)ws;
    u16*   W2r     = (u16*)(ws + W2R_OFF);
    u16*   Woff2   = (u16*)(ws + WOFF2_OFF);
    float* off_ws  = (float*)(ws + OFFWS_OFF);
    int4*  G_off   = (int4*)(ws + GOFF_OFF);
    float4* G_w    = (float4*)(ws + GW_OFF);

    hipMemsetAsync(xT, 0, XT_BYTES, stream);
    k_prep<<<2592, 256, 0, stream>>>(w, w_off, W2r, Woff2);
    k_transpose<<<dim3(4, 64, 8), 256, 0, stream>>>(x, xT);
    k_offconv<<<dim3(32, 8), 256, 0, stream>>>(xT, Woff2, b_off, off_ws);
    k_coords<<<1152, 256, 0, stream>>>(off_ws, G_off, G_w);
    k_main<<<dim3(32, 2, 8), 256, 0, stream>>>(xT, W2r, G_off, G_w, bias, out);
}